// Round 2
// baseline (159.015 us; speedup 1.0000x reference)
//
#include <hip/hip_runtime.h>
#include <hip/hip_bf16.h>

#define BATCH 32
#define LL 512
#define DD 768
#define EPSC 1e-5f

typedef __attribute__((ext_vector_type(8))) short bf16x8;
typedef __attribute__((ext_vector_type(4))) float f32x4;

// ---------------------------------------------------------------------------
// Kernel 1: per-row scale s[b*L+l] = (eps + sum_d x^2)^(1/4)
// One wave per row (768 = 64 lanes * 3 float4).
// ---------------------------------------------------------------------------
__global__ __launch_bounds__(256) void k_scales(const float* __restrict__ x,
                                                float* __restrict__ s) {
    int wave = threadIdx.x >> 6;
    int lane = threadIdx.x & 63;
    int row = blockIdx.x * 4 + wave;                 // [0, 16384)
    const float4* xr = (const float4*)(x + (size_t)row * DD);
    float sum = 0.f;
#pragma unroll
    for (int i = 0; i < 3; i++) {
        float4 v = xr[lane + i * 64];
        sum += v.x * v.x + v.y * v.y + v.z * v.z + v.w * v.w;
    }
#pragma unroll
    for (int off = 32; off > 0; off >>= 1)
        sum += __shfl_xor(sum, off, 64);
    if (lane == 0) s[row] = sqrtf(sqrtf(EPSC + sum));
}

// ---------------------------------------------------------------------------
// Kernel 2: Yt[b][d][l] = bf16( s[b][l] * x[b][l][d] )   (transpose via LDS)
// 64x64 tile, row stride 65 floats -> both phases bank-conflict-free.
// ---------------------------------------------------------------------------
__global__ __launch_bounds__(256) void k_transpose(const float* __restrict__ x,
                                                   const float* __restrict__ s,
                                                   ushort* __restrict__ yt) {
    __shared__ float tile[64][65];
    __shared__ float svec[64];
    int b = blockIdx.z;
    int l0 = blockIdx.y * 64;
    int d0 = blockIdx.x * 64;
    int t = threadIdx.x;
    if (t < 64) svec[t] = s[b * LL + l0 + t];
    const float* xp = x + ((size_t)b * LL + l0) * DD + d0;
    int f = t & 15, lr0 = t >> 4;                     // f: float4 col, lr0: row
#pragma unroll
    for (int r = 0; r < 4; r++) {
        int l = lr0 + r * 16;
        float4 v = *(const float4*)(xp + (size_t)l * DD + f * 4);
#pragma unroll
        for (int j = 0; j < 4; j++)
            tile[l][f * 4 + j] = ((const float*)&v)[j];
    }
    __syncthreads();
    ushort* yp = yt + ((size_t)b * DD + d0) * LL + l0;
    int lc = t & 7, dl0 = t >> 3;                     // lc: l-chunk, dl0: d row
#pragma unroll
    for (int it = 0; it < 2; it++) {
        int d = dl0 + it * 32;
        bf16x8 w;
#pragma unroll
        for (int j = 0; j < 8; j++) {
            int l = lc * 8 + j;
            float v = tile[l][d] * svec[l];
            __hip_bfloat16 h = __float2bfloat16(v);
            w[j] = *(short*)&h;
        }
        *(bf16x8*)(yp + (size_t)d * LL + lc * 8) = w;
    }
}

// ---------------------------------------------------------------------------
// Kernel 3: C[b] = Yt[b]*Yt[b]^T, symmetric. 64x64 tile per WAVE, fragments
// read DIRECTLY from global (Yt is L2-resident: 786 KB/batch, 4 batches/XCD
// = 3.1 MB < 4 MB L2). No LDS, no barriers, no vmcnt(0) drains -- removes
// the 16x per-block exposed-latency stalls of the staged version.
// 2496 blocks x 1 wave; XCD swizzle keeps each batch's Yt in one XCD's L2.
// ---------------------------------------------------------------------------
__global__ __launch_bounds__(64) void k_gemm(const ushort* __restrict__ yt,
                                             float* __restrict__ out) {
    int i = blockIdx.x;                               // [0, 2496)
    int xcd = i & 7, slot = i >> 3;                   // XCD round-robin
    int b = xcd + 8 * (slot / 78);
    int p = slot % 78;
    int t = p, tm = 0, rem = 12;
    while (t >= rem) { t -= rem; rem--; tm++; }
    int tn = tm + t;                                  // tm <= tn
    bool diag = (tm == tn);
    int m0 = tm * 64, n0 = tn * 64;
    int lane = threadIdx.x;                           // 64 threads = 1 wave
    int fr = lane & 15, ks4 = lane >> 4;              // frag row / k-slot
    const ushort* yb = yt + (size_t)b * DD * LL;
    const ushort* pa = yb + (size_t)(m0 + fr) * LL + ks4 * 8;
    const ushort* pb = yb + (size_t)(n0 + fr) * LL + ks4 * 8;
    if (diag) pb = pa;                                // diag: B = A (uniform code)

    f32x4 acc[4][4];
#pragma unroll
    for (int ii = 0; ii < 4; ii++)
#pragma unroll
        for (int j = 0; j < 4; j++) acc[ii][j] = (f32x4){0.f, 0.f, 0.f, 0.f};

#pragma unroll 2
    for (int ks = 0; ks < 16; ks++) {
        bf16x8 af[4], bg[4];
#pragma unroll
        for (int ii = 0; ii < 4; ii++)
            af[ii] = *(const bf16x8*)(pa + (size_t)ii * 16 * LL + ks * 32);
#pragma unroll
        for (int j = 0; j < 4; j++)
            bg[j] = *(const bf16x8*)(pb + (size_t)j * 16 * LL + ks * 32);
#pragma unroll
        for (int ii = 0; ii < 4; ii++)
#pragma unroll
            for (int j = 0; j < 4; j++)
                acc[ii][j] = __builtin_amdgcn_mfma_f32_16x16x32_bf16(
                    af[ii], bg[j], acc[ii][j], 0, 0, 0);
    }

    // Epilogue. C/D layout: col = lane&15, row = (lane>>4)*4 + r.
    // Mirror (transposed) write is float4; direct write scalar (off-diag).
    float* op = out + (size_t)b * DD * DD;
#pragma unroll
    for (int ii = 0; ii < 4; ii++) {
        int colb = m0 + ii * 16 + ks4 * 4;
#pragma unroll
        for (int j = 0; j < 4; j++) {
            int row = n0 + j * 16 + fr;
            float4 v = {acc[ii][j][0], acc[ii][j][1], acc[ii][j][2], acc[ii][j][3]};
            *(float4*)(op + (size_t)row * DD + colb) = v;   // mirror (or diag)
        }
    }
    if (!diag) {
#pragma unroll
        for (int ii = 0; ii < 4; ii++) {
            int mbase = m0 + ii * 16 + ks4 * 4;
#pragma unroll
            for (int j = 0; j < 4; j++) {
                int n = n0 + j * 16 + fr;
#pragma unroll
                for (int r = 0; r < 4; r++)
                    op[(size_t)(mbase + r) * DD + n] = acc[ii][j][r];
            }
        }
    }
}

// ---------------------------------------------------------------------------
extern "C" void kernel_launch(void* const* d_in, const int* in_sizes, int n_in,
                              void* d_out, int out_size, void* d_ws, size_t ws_size,
                              hipStream_t stream) {
    const float* x = (const float*)d_in[0];
    float* s = (float*)d_ws;                                        // 64 KB
    ushort* yt = (ushort*)((char*)d_ws + 65536);                    // 25.2 MB bf16

    k_scales<<<dim3((BATCH * LL) / 4), 256, 0, stream>>>(x, s);
    k_transpose<<<dim3(DD / 64, LL / 64, BATCH), 256, 0, stream>>>(x, s, yt);
    k_gemm<<<dim3(78 * BATCH), 64, 0, stream>>>(yt, (float*)d_out);
}